// Round 6
// baseline (1127.259 us; speedup 1.0000x reference)
//
#include <hip/hip_runtime.h>
#include <hip/hip_bf16.h>

#define IN_F 256
#define NN   2048
#define BB   8
#define ROWS 8
#define NEGV (-9.0e15f)

// ---------------------------------------------------------------------------
// Kernel 1 (1 block): v1[k] = sum_c W1[k,c]*a1[c], v2[k] = sum_c W1[k,c]*a2[c]
// (associativity: Wh1 = (h@W1)·a1 = h·(W1@a1))
// ---------------------------------------------------------------------------
__global__ __launch_bounds__(256) void calc_v(const float* __restrict__ W1,
                                              const float* __restrict__ a,
                                              float* __restrict__ v1,
                                              float* __restrict__ v2)
{
    __shared__ float s1[IN_F], s2[IN_F];
    const int t = threadIdx.x;
    s1[t] = a[t];
    s2[t] = a[IN_F + t];
    __syncthreads();
    float acc1 = 0.f, acc2 = 0.f;
    for (int c = 0; c < IN_F; ++c) {
        float w = W1[t * IN_F + c];
        acc1 += w * s1[c];
        acc2 += w * s2[c];
    }
    v1[t] = acc1;
    v2[t] = acc2;
}

// ---------------------------------------------------------------------------
// Kernel 2: Wh1[row] = h[row,:]·v1, Wh2[row] = h[row,:]·v2. One wave per row.
// ---------------------------------------------------------------------------
__global__ __launch_bounds__(256) void rowdots(const float* __restrict__ h,
                                               const float* __restrict__ v1,
                                               const float* __restrict__ v2,
                                               float* __restrict__ Wh1,
                                               float* __restrict__ Wh2)
{
    const int wave = threadIdx.x >> 6;
    const int lane = threadIdx.x & 63;
    const long row = (long)blockIdx.x * 4 + wave;
    const int c0 = lane * 4;

    float4 v  = *(const float4*)(h + row * IN_F + c0);
    float4 a1 = *(const float4*)(v1 + c0);
    float4 a2 = *(const float4*)(v2 + c0);

    float s1 = v.x * a1.x + v.y * a1.y + v.z * a1.z + v.w * a1.w;
    float s2 = v.x * a2.x + v.y * a2.y + v.z * a2.z + v.w * a2.w;
#pragma unroll
    for (int off = 32; off; off >>= 1) {
        s1 += __shfl_xor(s1, off, 64);
        s2 += __shfl_xor(s2, off, 64);
    }
    if (lane == 0) { Wh1[row] = s1; Wh2[row] = s2; }
}

// ---------------------------------------------------------------------------
// Kernel 3: flash-style masked softmax over j + dual aggregation of raw
// (h, lrgt1), then per-block epilogue GEMM with W1/W2 and ELU. fp32 out.
//   h'  = softmax(mask(leakyrelu(Wh1_i+Wh2_j))) @ h     @ W1
//   gt' = same attention                        @ lrgt1 @ W2
// ---------------------------------------------------------------------------
__global__ __launch_bounds__(256) void attn(const int*   __restrict__ adj,
                                            const float* __restrict__ h,
                                            const float* __restrict__ g,
                                            const float* __restrict__ Wh1,
                                            const float* __restrict__ Wh2,
                                            const float* __restrict__ W1,
                                            const float* __restrict__ W2,
                                            float* __restrict__ out)
{
    const int t = threadIdx.x;
    const int wave = t >> 6;
    const int lane = t & 63;
    const int blocksPerBatch = NN / ROWS;
    const int b  = blockIdx.x / blocksPerBatch;
    const int i0 = (blockIdx.x % blocksPerBatch) * ROWS;
    const long bN = (long)b * NN;

    __shared__ float sp[ROWS][IN_F];     // logits -> p; epilogue: aggH
    __shared__ float sg[ROWS][IN_F];     // epilogue: aggG
    __shared__ float redmax[ROWS];
    __shared__ float redsum[ROWS];

    float wh1r[ROWS];
#pragma unroll
    for (int r = 0; r < ROWS; ++r) wh1r[r] = Wh1[bN + i0 + r];

    float m[ROWS], l[ROWS], accH[ROWS], accG[ROWS];
#pragma unroll
    for (int r = 0; r < ROWS; ++r) {
        m[r] = -3.0e38f;     // finite sentinel
        l[r] = 0.f;
        accH[r] = 0.f;
        accG[r] = 0.f;
    }

    for (int jt = 0; jt < NN / 256; ++jt) {
        const int j = jt * 256 + t;
        const float wh2 = Wh2[bN + j];

        __syncthreads();   // A: previous tile's phase-3 sp reads done
#pragma unroll
        for (int r = 0; r < ROWS; ++r) {
            int av = adj[(bN + i0 + r) * (long)NN + j];
            float e = wh1r[r] + wh2;
            e = (e >= 0.f) ? e : 0.2f * e;
            sp[r][t] = (av > 0) ? e : NEGV;
        }
        __syncthreads();   // B

        // tile max per row (wave w handles rows w, w+4)
        for (int rr = wave; rr < ROWS; rr += 4) {
            float v = fmaxf(fmaxf(sp[rr][lane], sp[rr][lane + 64]),
                            fmaxf(sp[rr][lane + 128], sp[rr][lane + 192]));
#pragma unroll
            for (int off = 32; off; off >>= 1)
                v = fmaxf(v, __shfl_xor(v, off, 64));
            if (lane == 0) redmax[rr] = v;
        }
        __syncthreads();   // C

        float alpha[ROWS];
#pragma unroll
        for (int r = 0; r < ROWS; ++r) {
            float mn = fmaxf(m[r], redmax[r]);
            alpha[r] = __expf(m[r] - mn);
            sp[r][t] = __expf(sp[r][t] - mn);
            m[r] = mn;
        }
        __syncthreads();   // D

        // tile sum per row
        for (int rr = wave; rr < ROWS; rr += 4) {
            float v = sp[rr][lane] + sp[rr][lane + 64] +
                      sp[rr][lane + 128] + sp[rr][lane + 192];
#pragma unroll
            for (int off = 32; off; off >>= 1)
                v += __shfl_xor(v, off, 64);
            if (lane == 0) redsum[rr] = v;
        }
        __syncthreads();   // E

#pragma unroll
        for (int r = 0; r < ROWS; ++r) {
            l[r] = l[r] * alpha[r] + redsum[r];
            accH[r] *= alpha[r];
            accG[r] *= alpha[r];
        }

        // phase 3: acc += p(tile) * h/g tile rows.  thread = column t.
        const float* hp = h + (bN + (long)jt * 256) * IN_F + t;
        const float* gp = g + (bN + (long)jt * 256) * IN_F + t;
#pragma unroll 2
        for (int tt = 0; tt < 256; tt += 4) {
            float wv0 = hp[(long)(tt + 0) * IN_F];
            float wv1 = hp[(long)(tt + 1) * IN_F];
            float wv2 = hp[(long)(tt + 2) * IN_F];
            float wv3 = hp[(long)(tt + 3) * IN_F];
            float gv0 = gp[(long)(tt + 0) * IN_F];
            float gv1 = gp[(long)(tt + 1) * IN_F];
            float gv2 = gp[(long)(tt + 2) * IN_F];
            float gv3 = gp[(long)(tt + 3) * IN_F];
#pragma unroll
            for (int r = 0; r < ROWS; ++r) {
                float4 p = *(const float4*)&sp[r][tt];   // LDS broadcast b128
                accH[r] += p.x * wv0 + p.y * wv1 + p.z * wv2 + p.w * wv3;
                accG[r] += p.x * gv0 + p.y * gv1 + p.z * gv2 + p.w * gv3;
            }
        }
    }

    // ---- epilogue: normalize -> LDS, mini-GEMM with W1/W2, ELU, store ----
    __syncthreads();
#pragma unroll
    for (int r = 0; r < ROWS; ++r) {
        float inv = 1.0f / l[r];
        sp[r][t] = accH[r] * inv;    // (attention @ h)[i0+r, t]
        sg[r][t] = accG[r] * inv;    // (attention @ lrgt1)[i0+r, t]
    }
    __syncthreads();

    float oH[ROWS], oG[ROWS];
#pragma unroll
    for (int r = 0; r < ROWS; ++r) { oH[r] = 0.f; oG[r] = 0.f; }

    for (int k = 0; k < IN_F; k += 4) {
        const float w10 = W1[(k + 0) * IN_F + t];
        const float w11 = W1[(k + 1) * IN_F + t];
        const float w12 = W1[(k + 2) * IN_F + t];
        const float w13 = W1[(k + 3) * IN_F + t];
        const float w20 = W2[(k + 0) * IN_F + t];
        const float w21 = W2[(k + 1) * IN_F + t];
        const float w22 = W2[(k + 2) * IN_F + t];
        const float w23 = W2[(k + 3) * IN_F + t];
#pragma unroll
        for (int r = 0; r < ROWS; ++r) {
            float4 x = *(const float4*)&sp[r][k];
            oH[r] += x.x * w10 + x.y * w11 + x.z * w12 + x.w * w13;
            float4 y = *(const float4*)&sg[r][k];
            oG[r] += y.x * w20 + y.y * w21 + y.z * w22 + y.w * w23;
        }
    }

    const long outOfs = (long)BB * NN * IN_F;
#pragma unroll
    for (int r = 0; r < ROWS; ++r) {
        float hv = oH[r];
        float gv = oG[r];
        hv = (hv > 0.f) ? hv : (__expf(hv) - 1.f);   // ELU
        gv = (gv > 0.f) ? gv : (__expf(gv) - 1.f);
        long oi = (bN + i0 + r) * IN_F + t;
        out[oi] = hv;              // fp32 output, first tuple element
        out[outOfs + oi] = gv;     // fp32 output, second tuple element
    }
}

// ---------------------------------------------------------------------------
extern "C" void kernel_launch(void* const* d_in, const int* in_sizes, int n_in,
                              void* d_out, int out_size, void* d_ws, size_t ws_size,
                              hipStream_t stream)
{
    // identify inputs by element count (robust to ordering):
    // adj = 8*2048*2048 ; h,lrgt1 = 8*2048*256 (in order) ; W1,W2 = 65536 ; a = 512
    int ih = -1, ig = -1, iadj = -1, iw1 = -1, iw2 = -1, ia = -1;
    for (int i = 0; i < n_in; ++i) {
        int s = in_sizes[i];
        if      (s == BB * NN * NN)   { if (iadj < 0) iadj = i; }
        else if (s == BB * NN * IN_F) { if (ih < 0) ih = i; else if (ig < 0) ig = i; }
        else if (s == IN_F * IN_F)    { if (iw1 < 0) iw1 = i; else if (iw2 < 0) iw2 = i; }
        else if (s == 2 * IN_F)       { if (ia < 0) ia = i; }
    }
    if (ih < 0 || ig < 0 || iadj < 0 || iw1 < 0 || iw2 < 0 || ia < 0) {
        ih = 0; iadj = 1; ig = 2; iw1 = 3; iw2 = 4; ia = 5;  // documented order
    }
    const float* h     = (const float*)d_in[ih];
    const int*   adj   = (const int*)  d_in[iadj];
    const float* lrgt1 = (const float*)d_in[ig];
    const float* W1    = (const float*)d_in[iw1];
    const float* W2    = (const float*)d_in[iw2];
    const float* a     = (const float*)d_in[ia];
    float* out = (float*)d_out;   // reference outputs are float32

    // ws layout (fp32 units): v1[256] | v2[256] | Wh1[16384] | Wh2[16384]
    float* ws  = (float*)d_ws;
    float* v1  = ws;
    float* v2  = v1 + IN_F;
    float* Wh1 = v2 + IN_F;
    float* Wh2 = Wh1 + (long)BB * NN;   // total ~132 KB

    const int nrows = BB * NN;

    calc_v <<<1, 256, 0, stream>>>(W1, a, v1, v2);
    rowdots<<<nrows / 4, 256, 0, stream>>>(h, v1, v2, Wh1, Wh2);
    attn   <<<nrows / ROWS, 256, 0, stream>>>(adj, h, lrgt1, Wh1, Wh2, W1, W2, out);
}

// Round 9
// 461.291 us; speedup vs baseline: 2.4437x; 2.4437x over previous
//
#include <hip/hip_runtime.h>
#include <hip/hip_bf16.h>

#define IN_F 256
#define NN   2048
#define BB   8
#define NEGV (-9.0e15f)

typedef unsigned short u16;
typedef __attribute__((ext_vector_type(8))) short short8x;   // 8 bf16 = 4 VGPRs
typedef __attribute__((ext_vector_type(4))) float float4x;   // MFMA acc

// fp32 -> bf16 bits, round-to-nearest-even
__device__ __forceinline__ u16 f2b(float f) {
    union { float f; unsigned int u; } x; x.f = f;
    unsigned int r = x.u + 0x7FFFu + ((x.u >> 16) & 1u);
    return (u16)(r >> 16);
}

__device__ __forceinline__ float logitf(float wh1v, float w, int av) {
    float e = wh1v + w;
    e = (e >= 0.f) ? e : 0.2f * e;
    return (av > 0) ? e : NEGV;
}

// ---------------------------------------------------------------------------
// prep: fused transposes (h->HbfT, lrgt1->GbfT, W1->W1T, W2->W2T) + calc_v.
// Block roles by blockIdx; all blocks independent.
// ---------------------------------------------------------------------------
__device__ __forceinline__ void transp_body(const float* __restrict__ src,
                                            u16* __restrict__ dst,
                                            int R, int C, int tid,
                                            float (*tile)[33])
{
    const int per = (R / 32) * (C / 32);
    const int b  = tid / per;
    const int tt = tid % per;
    const int jt = tt / (C / 32);
    const int ct = tt % (C / 32);
    src += (long)b * R * C;
    dst += (long)b * R * C;

    const int tx = threadIdx.x & 31, ty = threadIdx.x >> 5;
#pragma unroll
    for (int i = 0; i < 4; ++i)
        tile[ty + i * 8][tx] = src[(long)(jt * 32 + ty + i * 8) * C + ct * 32 + tx];
    __syncthreads();
#pragma unroll
    for (int i = 0; i < 4; ++i)
        dst[(long)(ct * 32 + ty + i * 8) * R + jt * 32 + tx] = f2b(tile[tx][ty + i * 8]);
}

__global__ __launch_bounds__(256) void prep(const float* __restrict__ h,
                                            const float* __restrict__ g,
                                            const float* __restrict__ W1,
                                            const float* __restrict__ W2,
                                            const float* __restrict__ a,
                                            u16* __restrict__ HbfT,
                                            u16* __restrict__ GbfT,
                                            u16* __restrict__ W1T,
                                            u16* __restrict__ W2T,
                                            float* __restrict__ v1,
                                            float* __restrict__ v2)
{
    __shared__ float tile[32][33];
    __shared__ float s1[IN_F], s2[IN_F];
    const int bid = blockIdx.x;

    if (bid < 4096) {
        transp_body(h, HbfT, NN, IN_F, bid, tile);
    } else if (bid < 8192) {
        transp_body(g, GbfT, NN, IN_F, bid - 4096, tile);
    } else if (bid < 8256) {
        transp_body(W1, W1T, IN_F, IN_F, bid - 8192, tile);
    } else if (bid < 8320) {
        transp_body(W2, W2T, IN_F, IN_F, bid - 8256, tile);
    } else {
        // calc_v: v1[k] = sum_c W1[k,c]*a1[c], v2[k] = sum_c W1[k,c]*a2[c]
        const int t = threadIdx.x;
        s1[t] = a[t];
        s2[t] = a[IN_F + t];
        __syncthreads();
        float acc1 = 0.f, acc2 = 0.f;
        for (int c = 0; c < IN_F; ++c) {
            float w = W1[t * IN_F + c];
            acc1 += w * s1[c];
            acc2 += w * s2[c];
        }
        v1[t] = acc1;
        v2[t] = acc2;
    }
}

// ---------------------------------------------------------------------------
// rowdots: Wh1[row] = h[row,:]·v1, Wh2[row] = h[row,:]·v2. One wave per row.
// ---------------------------------------------------------------------------
__global__ __launch_bounds__(256) void rowdots(const float* __restrict__ h,
                                               const float* __restrict__ v1,
                                               const float* __restrict__ v2,
                                               float* __restrict__ Wh1,
                                               float* __restrict__ Wh2)
{
    const int wave = threadIdx.x >> 6;
    const int lane = threadIdx.x & 63;
    const long row = (long)blockIdx.x * 4 + wave;
    const int c0 = lane * 4;

    float4 v  = *(const float4*)(h + row * IN_F + c0);
    float4 a1 = *(const float4*)(v1 + c0);
    float4 a2 = *(const float4*)(v2 + c0);

    float s1 = v.x * a1.x + v.y * a1.y + v.z * a1.z + v.w * a1.w;
    float s2 = v.x * a2.x + v.y * a2.y + v.z * a2.z + v.w * a2.w;
#pragma unroll
    for (int off = 32; off; off >>= 1) {
        s1 += __shfl_xor(s1, off, 64);
        s2 += __shfl_xor(s2, off, 64);
    }
    if (lane == 0) { Wh1[row] = s1; Wh2[row] = s2; }
}

// ---------------------------------------------------------------------------
// attn_mfma with FUSED per-block softmax stats.
// Block = 32 rows x 256 cols. Phase S: compute m,l for the block's own rows
// (two passes over its adj slice, 8 threads/row). Then the proven K-loop:
// generate normalized bf16 P-tiles in LDS (A-fragment order) and MFMA against
// transposed HbfT/GbfT. Writes P@h, P@g as bf16.
// ---------------------------------------------------------------------------
__global__ __launch_bounds__(256) void attn_mfma(
    const int* __restrict__ adj,
    const u16* __restrict__ HbfT, const u16* __restrict__ GbfT,
    const float* __restrict__ Wh1, const float* __restrict__ Wh2,
    u16* __restrict__ PH, u16* __restrict__ PG)
{
    const int t = threadIdx.x;
    const int wave = t >> 6, lane = t & 63;
    const int b = blockIdx.x >> 6;            // 64 row-blocks per batch
    const long gi0 = (long)blockIdx.x * 32;   // global row base

    __shared__ __align__(16) u16 Afrag[4 * 2 * 64 * 8];   // 8 KB
    __shared__ float sred[32][8];
    __shared__ float smv[32];
    __shared__ float silv[32];

    // thread role (both phases): row rr = t>>3 of the 32, segment seg = t&7
    const int rr = t >> 3, seg = t & 7;
    const long adjR = (gi0 + rr) * (long)NN;
    const float* wh2b = Wh2 + (long)b * NN;
    const float wh1rr = Wh1[gi0 + rr];

    // ---- phase S1: row max (each thread scans 256 j) ----
    float mx = -3.0e38f;
#pragma unroll 8
    for (int it = 0; it < 64; ++it) {
        const int j = seg * 256 + it * 4;
        int4   av = *(const int4*)(adj + adjR + j);
        float4 w  = *(const float4*)(wh2b + j);
        mx = fmaxf(mx, logitf(wh1rr, w.x, av.x));
        mx = fmaxf(mx, logitf(wh1rr, w.y, av.y));
        mx = fmaxf(mx, logitf(wh1rr, w.z, av.z));
        mx = fmaxf(mx, logitf(wh1rr, w.w, av.w));
    }
    sred[rr][seg] = mx;
    __syncthreads();
    if (t < 32) {
        float v = sred[t][0];
#pragma unroll
        for (int k = 1; k < 8; ++k) v = fmaxf(v, sred[t][k]);
        smv[t] = v;
    }
    __syncthreads();
    const float mvv = smv[rr];

    // ---- phase S2: row sum of exp (adj slice now L1/L2-hot) ----
    float sum = 0.f;
#pragma unroll 8
    for (int it = 0; it < 64; ++it) {
        const int j = seg * 256 + it * 4;
        int4   av = *(const int4*)(adj + adjR + j);
        float4 w  = *(const float4*)(wh2b + j);
        sum += __expf(logitf(wh1rr, w.x, av.x) - mvv);
        sum += __expf(logitf(wh1rr, w.y, av.y) - mvv);
        sum += __expf(logitf(wh1rr, w.z, av.z) - mvv);
        sum += __expf(logitf(wh1rr, w.w, av.w) - mvv);
    }
    sred[rr][seg] = sum;
    __syncthreads();
    if (t < 32) {
        float v = sred[t][0];
#pragma unroll
        for (int k = 1; k < 8; ++k) v += sred[t][k];
        silv[t] = 1.0f / v;     // v >= 1 always (max-subtracted)
    }
    __syncthreads();

    // ---- K-loop (identical to the call-1-proven R7 body) ----
    float4x accH[2][4], accG[2][4];
#pragma unroll
    for (int rt = 0; rt < 2; ++rt)
#pragma unroll
        for (int ct = 0; ct < 4; ++ct) {
            accH[rt][ct] = (float4x)0.0f;
            accG[rt][ct] = (float4x)0.0f;
        }

    const int pm  = rr;                       // P-gen row
    const int kb  = seg * 16;                 // P-gen k-slice base
    const int prt = pm >> 4, plm = pm & 15;
    const float mv  = smv[pm];
    const float ilv = silv[pm];

    const int bn = lane & 15, bq = lane >> 4;
    const long hbase = (long)b * IN_F * NN;

    for (int j0 = 0; j0 < NN; j0 += 128) {
        __syncthreads();     // protect Afrag from previous iteration's readers
#pragma unroll
        for (int half = 0; half < 2; ++half) {
            const int k8 = kb + half * 8;
            const int j  = j0 + k8;
            int4   a0 = *(const int4*)(adj + adjR + j);
            int4   a1 = *(const int4*)(adj + adjR + j + 4);
            float4 w0 = *(const float4*)(wh2b + j);
            float4 w1 = *(const float4*)(wh2b + j + 4);
            union { short8x v; u16 u[8]; } pk;
            pk.u[0] = f2b(__expf(logitf(wh1rr, w0.x, a0.x) - mv) * ilv);
            pk.u[1] = f2b(__expf(logitf(wh1rr, w0.y, a0.y) - mv) * ilv);
            pk.u[2] = f2b(__expf(logitf(wh1rr, w0.z, a0.z) - mv) * ilv);
            pk.u[3] = f2b(__expf(logitf(wh1rr, w0.w, a0.w) - mv) * ilv);
            pk.u[4] = f2b(__expf(logitf(wh1rr, w1.x, a1.x) - mv) * ilv);
            pk.u[5] = f2b(__expf(logitf(wh1rr, w1.y, a1.y) - mv) * ilv);
            pk.u[6] = f2b(__expf(logitf(wh1rr, w1.z, a1.z) - mv) * ilv);
            pk.u[7] = f2b(__expf(logitf(wh1rr, w1.w, a1.w) - mv) * ilv);
            const int ks = k8 >> 5, kk = k8 & 31;
            const int wl = plm + ((kk >> 3) << 4);   // A-fragment lane
            *(short8x*)&Afrag[((ks * 2 + prt) * 64 + wl) * 8] = pk.v;
        }
        __syncthreads();

#pragma unroll
        for (int ks = 0; ks < 4; ++ks) {
            short8x A0 = *(const short8x*)&Afrag[((ks * 2 + 0) * 64 + lane) * 8];
            short8x A1 = *(const short8x*)&Afrag[((ks * 2 + 1) * 64 + lane) * 8];
            const int jj = j0 + ks * 32 + bq * 8;
#pragma unroll
            for (int ct = 0; ct < 4; ++ct) {
                const int c = wave * 64 + ct * 16 + bn;
                const long bi = hbase + (long)c * NN + jj;
                short8x Bh = *(const short8x*)(HbfT + bi);
                short8x Bg = *(const short8x*)(GbfT + bi);
                accH[0][ct] = __builtin_amdgcn_mfma_f32_16x16x32_bf16(A0, Bh, accH[0][ct], 0, 0, 0);
                accH[1][ct] = __builtin_amdgcn_mfma_f32_16x16x32_bf16(A1, Bh, accH[1][ct], 0, 0, 0);
                accG[0][ct] = __builtin_amdgcn_mfma_f32_16x16x32_bf16(A0, Bg, accG[0][ct], 0, 0, 0);
                accG[1][ct] = __builtin_amdgcn_mfma_f32_16x16x32_bf16(A1, Bg, accG[1][ct], 0, 0, 0);
            }
        }
    }

    // C-layout: col = lane&15, row = (lane>>4)*4 + reg  (P pre-normalized)
#pragma unroll
    for (int rt = 0; rt < 2; ++rt)
#pragma unroll
        for (int ct = 0; ct < 4; ++ct) {
            const int c = wave * 64 + ct * 16 + bn;
#pragma unroll
            for (int reg = 0; reg < 4; ++reg) {
                const long row = gi0 + rt * 16 + bq * 4 + reg;
                PH[row * IN_F + c] = f2b(accH[rt][ct][reg]);
                PG[row * IN_F + c] = f2b(accG[rt][ct][reg]);
            }
        }
}

// ---------------------------------------------------------------------------
// epi2: both epilogue GEMMs in one launch.
// blocks [0,512): out0 = ELU(PH @ W1); blocks [512,1024): out1 = ELU(PG @ W2)
// ---------------------------------------------------------------------------
__global__ __launch_bounds__(256) void epi2(const u16* __restrict__ PH,
                                            const u16* __restrict__ PG,
                                            const u16* __restrict__ W1T,
                                            const u16* __restrict__ W2T,
                                            float* __restrict__ out)
{
    int bid = blockIdx.x;
    const u16* X;
    const u16* WT;
    float* o;
    if (bid < 512) { X = PH; WT = W1T; o = out; }
    else           { X = PG; WT = W2T; o = out + (long)BB * NN * IN_F; bid -= 512; }

    const int t = threadIdx.x;
    const int wave = t >> 6, lane = t & 63;
    const long i0 = (long)bid * 32;

    __shared__ __align__(16) u16 Afrag[8 * 2 * 64 * 8];   // 16 KB

    const int m = t >> 3, ks0 = t & 7, rt0 = m >> 4, lm = m & 15;
    const u16* xp = X + (i0 + m) * IN_F + ks0 * 32;
#pragma unroll
    for (int q = 0; q < 4; ++q) {
        short8x v = *(const short8x*)(xp + q * 8);
        *(short8x*)&Afrag[((ks0 * 2 + rt0) * 64 + lm + q * 16) * 8] = v;
    }
    __syncthreads();

    float4x acc[2][4];
#pragma unroll
    for (int rt = 0; rt < 2; ++rt)
#pragma unroll
        for (int ct = 0; ct < 4; ++ct) acc[rt][ct] = (float4x)0.0f;

    const int bn = lane & 15, bq = lane >> 4;
#pragma unroll
    for (int ks = 0; ks < 8; ++ks) {
        short8x A0 = *(const short8x*)&Afrag[((ks * 2 + 0) * 64 + lane) * 8];
        short8x A1 = *(const short8x*)&Afrag[((ks * 2 + 1) * 64 + lane) * 8];
#pragma unroll
        for (int ct = 0; ct < 4; ++ct) {
            const int n = wave * 64 + ct * 16 + bn;
            short8x Bw = *(const short8x*)(WT + n * IN_F + ks * 32 + bq * 8);
            acc[0][ct] = __builtin_amdgcn_mfma_f32_16x16x32_bf16(A0, Bw, acc[0][ct], 0, 0, 0);
            acc[1][ct] = __builtin_amdgcn_mfma_f32_16x16x32_bf16(A1, Bw, acc[1][ct], 0, 0, 0);
        }
    }

#pragma unroll
    for (int rt = 0; rt < 2; ++rt)
#pragma unroll
        for (int ct = 0; ct < 4; ++ct) {
            const int n = wave * 64 + ct * 16 + bn;
#pragma unroll
            for (int reg = 0; reg < 4; ++reg) {
                const long row = i0 + rt * 16 + bq * 4 + reg;
                float v = acc[rt][ct][reg];
                v = (v > 0.f) ? v : (__expf(v) - 1.f);   // ELU
                o[row * IN_F + n] = v;
            }
        }
}

// ---------------------------------------------------------------------------
extern "C" void kernel_launch(void* const* d_in, const int* in_sizes, int n_in,
                              void* d_out, int out_size, void* d_ws, size_t ws_size,
                              hipStream_t stream)
{
    // identify inputs by element count (robust to ordering)
    int ih = -1, ig = -1, iadj = -1, iw1 = -1, iw2 = -1, ia = -1;
    for (int i = 0; i < n_in; ++i) {
        int s = in_sizes[i];
        if      (s == BB * NN * NN)   { if (iadj < 0) iadj = i; }
        else if (s == BB * NN * IN_F) { if (ih < 0) ih = i; else if (ig < 0) ig = i; }
        else if (s == IN_F * IN_F)    { if (iw1 < 0) iw1 = i; else if (iw2 < 0) iw2 = i; }
        else if (s == 2 * IN_F)       { if (ia < 0) ia = i; }
    }
    if (ih < 0 || ig < 0 || iadj < 0 || iw1 < 0 || iw2 < 0 || ia < 0) {
        ih = 0; iadj = 1; ig = 2; iw1 = 3; iw2 = 4; ia = 5;
    }
    const float* h     = (const float*)d_in[ih];
    const int*   adj   = (const int*)  d_in[iadj];
    const float* lrgt1 = (const float*)d_in[ig];
    const float* W1    = (const float*)d_in[iw1];
    const float* W2    = (const float*)d_in[iw2];
    const float* a     = (const float*)d_in[ia];
    float* out = (float*)d_out;

    // ws layout — 33,949,696 B total (<= proven-available 34,212,096 B)
    float* ws   = (float*)d_ws;
    float* v1   = ws;                       // 256
    float* v2   = v1 + IN_F;                // 256
    float* Wh1  = v2 + IN_F;                // 16384
    float* Wh2  = Wh1 + BB * NN;            // 16384
    u16* W1T  = (u16*)(Wh2 + BB * NN);      // 65536 bf16
    u16* W2T  = W1T + IN_F * IN_F;          // 65536
    u16* HbfT = W2T + IN_F * IN_F;          // 8*256*2048
    u16* GbfT = HbfT + (long)BB * IN_F * NN;
    u16* PH   = GbfT + (long)BB * IN_F * NN;
    u16* PG   = PH + (long)BB * NN * IN_F;

    const int nrows = BB * NN;

    prep     <<<8321,        256, 0, stream>>>(h, lrgt1, W1, W2, a,
                                               HbfT, GbfT, W1T, W2T, v1, v2);
    rowdots  <<<nrows / 4,   256, 0, stream>>>(h, v1, v2, Wh1, Wh2);
    attn_mfma<<<nrows / 32,  256, 0, stream>>>(adj, HbfT, GbfT, Wh1, Wh2, PH, PG);
    epi2     <<<2 * nrows / 32, 256, 0, stream>>>(PH, PG, W1T, W2T, out);
}

// Round 10
// 364.322 us; speedup vs baseline: 3.0941x; 1.2662x over previous
//
#include <hip/hip_runtime.h>
#include <hip/hip_bf16.h>

#define IN_F 256
#define NN   2048
#define BB   8
#define NEGV (-9.0e15f)

typedef unsigned short u16;
typedef __attribute__((ext_vector_type(8))) short short8x;   // 8 bf16 = 4 VGPRs
typedef __attribute__((ext_vector_type(4))) float float4x;   // MFMA acc

// fp32 -> bf16 bits, round-to-nearest-even
__device__ __forceinline__ u16 f2b(float f) {
    union { float f; unsigned int u; } x; x.f = f;
    unsigned int r = x.u + 0x7FFFu + ((x.u >> 16) & 1u);
    return (u16)(r >> 16);
}

__device__ __forceinline__ float logitf(float wh1v, float w, int av) {
    float e = wh1v + w;
    e = (e >= 0.f) ? e : 0.2f * e;
    return (av > 0) ? e : NEGV;
}

// ---------------------------------------------------------------------------
// prep: fused transposes (h->HbfT, lrgt1->GbfT, W1->W1T, W2->W2T) + calc_v.
// ---------------------------------------------------------------------------
__device__ __forceinline__ void transp_body(const float* __restrict__ src,
                                            u16* __restrict__ dst,
                                            int R, int C, int tid,
                                            float (*tile)[33])
{
    const int per = (R / 32) * (C / 32);
    const int b  = tid / per;
    const int tt = tid % per;
    const int jt = tt / (C / 32);
    const int ct = tt % (C / 32);
    src += (long)b * R * C;
    dst += (long)b * R * C;

    const int tx = threadIdx.x & 31, ty = threadIdx.x >> 5;
#pragma unroll
    for (int i = 0; i < 4; ++i)
        tile[ty + i * 8][tx] = src[(long)(jt * 32 + ty + i * 8) * C + ct * 32 + tx];
    __syncthreads();
#pragma unroll
    for (int i = 0; i < 4; ++i)
        dst[(long)(ct * 32 + ty + i * 8) * R + jt * 32 + tx] = f2b(tile[tx][ty + i * 8]);
}

__global__ __launch_bounds__(256) void prep(const float* __restrict__ h,
                                            const float* __restrict__ g,
                                            const float* __restrict__ W1,
                                            const float* __restrict__ W2,
                                            const float* __restrict__ a,
                                            u16* __restrict__ HbfT,
                                            u16* __restrict__ GbfT,
                                            u16* __restrict__ W1T,
                                            u16* __restrict__ W2T,
                                            float* __restrict__ v1,
                                            float* __restrict__ v2)
{
    __shared__ float tile[32][33];
    __shared__ float s1[IN_F], s2[IN_F];
    const int bid = blockIdx.x;

    if (bid < 4096) {
        transp_body(h, HbfT, NN, IN_F, bid, tile);
    } else if (bid < 8192) {
        transp_body(g, GbfT, NN, IN_F, bid - 4096, tile);
    } else if (bid < 8256) {
        transp_body(W1, W1T, IN_F, IN_F, bid - 8192, tile);
    } else if (bid < 8320) {
        transp_body(W2, W2T, IN_F, IN_F, bid - 8256, tile);
    } else {
        const int t = threadIdx.x;
        s1[t] = a[t];
        s2[t] = a[IN_F + t];
        __syncthreads();
        float acc1 = 0.f, acc2 = 0.f;
        for (int c = 0; c < IN_F; ++c) {
            float w = W1[t * IN_F + c];
            acc1 += w * s1[c];
            acc2 += w * s2[c];
        }
        v1[t] = acc1;
        v2[t] = acc2;
    }
}

// ---------------------------------------------------------------------------
// rowdots: Wh1[row] = h[row,:]·v1, Wh2[row] = h[row,:]·v2. One wave per row.
// ---------------------------------------------------------------------------
__global__ __launch_bounds__(256) void rowdots(const float* __restrict__ h,
                                               const float* __restrict__ v1,
                                               const float* __restrict__ v2,
                                               float* __restrict__ Wh1,
                                               float* __restrict__ Wh2)
{
    const int wave = threadIdx.x >> 6;
    const int lane = threadIdx.x & 63;
    const long row = (long)blockIdx.x * 4 + wave;
    const int c0 = lane * 4;

    float4 v  = *(const float4*)(h + row * IN_F + c0);
    float4 a1 = *(const float4*)(v1 + c0);
    float4 a2 = *(const float4*)(v2 + c0);

    float s1 = v.x * a1.x + v.y * a1.y + v.z * a1.z + v.w * a1.w;
    float s2 = v.x * a2.x + v.y * a2.y + v.z * a2.z + v.w * a2.w;
#pragma unroll
    for (int off = 32; off; off >>= 1) {
        s1 += __shfl_xor(s1, off, 64);
        s2 += __shfl_xor(s2, off, 64);
    }
    if (lane == 0) { Wh1[row] = s1; Wh2[row] = s2; }
}

// ---------------------------------------------------------------------------
// attn_mfma, single-pass: upper-bound max (lrelu(Wh1_i + max_j Wh2_j)),
// unnormalized P into MFMAs, per-row l accumulated in the same pass,
// 1/l applied in the epilogue. 512 threads (8 waves, wave = 32 cols),
// double-buffered Afrag + register prefetch, ONE barrier per K-chunk.
// ---------------------------------------------------------------------------
__global__ __launch_bounds__(512, 4) void attn_mfma(
    const int* __restrict__ adj,
    const u16* __restrict__ HbfT, const u16* __restrict__ GbfT,
    const float* __restrict__ Wh1, const float* __restrict__ Wh2,
    u16* __restrict__ PH, u16* __restrict__ PG)
{
    const int t = threadIdx.x;
    const int wave = t >> 6, lane = t & 63;
    const int b = blockIdx.x >> 6;            // 64 row-blocks per batch
    const long gi0 = (long)blockIdx.x * 32;   // global row base

    __shared__ __align__(16) u16 Afrag[2][4096];   // 2 x 8 KB
    __shared__ float sred[512];
    __shared__ float ssc[33];                      // [0..31]=1/l, [32]=wh2max

    // thread role: row rr (32), segment sg (16) -> 8 consecutive j per chunk
    const int rr = t >> 4, sg = t & 15;
    const long adjR = (gi0 + rr) * (long)NN;
    const float* wh2b = Wh2 + (long)b * NN;
    const float wh1rr = Wh1[gi0 + rr];

    // ---- per-batch max of Wh2 (8 KB, L2-hot) ----
    {
        float4 w = *(const float4*)(wh2b + t * 4);
        sred[t] = fmaxf(fmaxf(w.x, w.y), fmaxf(w.z, w.w));
    }
    __syncthreads();
    if (t < 64) {
        float v = sred[t * 8];
#pragma unroll
        for (int k = 1; k < 8; ++k) v = fmaxf(v, sred[t * 8 + k]);
#pragma unroll
        for (int off = 32; off; off >>= 1) v = fmaxf(v, __shfl_xor(v, off, 64));
        if (t == 0) ssc[32] = v;
    }
    __syncthreads();
    const float mm = wh1rr + ssc[32];
    const float mv = (mm >= 0.f) ? mm : 0.2f * mm;   // lrelu upper bound >= all logits

    // A-fragment write slot for this thread (16x16x32 A layout:
    // lane = m + 16*(k>>3), 8 k's per lane)
    const int ks0 = sg >> 2;
    const int wl  = (rr & 15) + ((sg & 3) << 4);
    const int prt = rr >> 4;
    const int aoff = ((ks0 * 2 + prt) * 64 + wl) * 8;

    float4x accH[2][2], accG[2][2];
#pragma unroll
    for (int rt = 0; rt < 2; ++rt)
#pragma unroll
        for (int ct = 0; ct < 2; ++ct) {
            accH[rt][ct] = (float4x)0.0f;
            accG[rt][ct] = (float4x)0.0f;
        }

    const int bn = lane & 15, bq = lane >> 4;
    const long hbase = (long)b * IN_F * NN;
    float lloc = 0.f;

    // prologue: load chunk 0
    int4   a0 = *(const int4*)(adj + adjR + sg * 8);
    int4   a1 = *(const int4*)(adj + adjR + sg * 8 + 4);
    float4 w0 = *(const float4*)(wh2b + sg * 8);
    float4 w1 = *(const float4*)(wh2b + sg * 8 + 4);

    for (int kch = 0; kch < 16; ++kch) {
        const int j0 = kch * 128;

        // compute unnormalized p (<= 1) from current regs
        union { short8x v; u16 u[8]; } pk;
        float p;
        p = __expf(logitf(wh1rr, w0.x, a0.x) - mv); lloc += p; pk.u[0] = f2b(p);
        p = __expf(logitf(wh1rr, w0.y, a0.y) - mv); lloc += p; pk.u[1] = f2b(p);
        p = __expf(logitf(wh1rr, w0.z, a0.z) - mv); lloc += p; pk.u[2] = f2b(p);
        p = __expf(logitf(wh1rr, w0.w, a0.w) - mv); lloc += p; pk.u[3] = f2b(p);
        p = __expf(logitf(wh1rr, w1.x, a1.x) - mv); lloc += p; pk.u[4] = f2b(p);
        p = __expf(logitf(wh1rr, w1.y, a1.y) - mv); lloc += p; pk.u[5] = f2b(p);
        p = __expf(logitf(wh1rr, w1.z, a1.z) - mv); lloc += p; pk.u[6] = f2b(p);
        p = __expf(logitf(wh1rr, w1.w, a1.w) - mv); lloc += p; pk.u[7] = f2b(p);

        // prefetch next chunk (in flight across the MFMA phase)
        if (kch < 15) {
            const long o = adjR + (kch + 1) * 128 + sg * 8;
            const int  w = (kch + 1) * 128 + sg * 8;
            a0 = *(const int4*)(adj + o);
            a1 = *(const int4*)(adj + o + 4);
            w0 = *(const float4*)(wh2b + w);
            w1 = *(const float4*)(wh2b + w + 4);
        }

        *(short8x*)&Afrag[kch & 1][aoff] = pk.v;
        __syncthreads();     // single barrier per chunk (double-buffered)

        const u16* ab = Afrag[kch & 1];
#pragma unroll
        for (int ks = 0; ks < 4; ++ks) {
            short8x A0 = *(const short8x*)&ab[((ks * 2 + 0) * 64 + lane) * 8];
            short8x A1 = *(const short8x*)&ab[((ks * 2 + 1) * 64 + lane) * 8];
            const int jj = j0 + ks * 32 + bq * 8;
#pragma unroll
            for (int ct = 0; ct < 2; ++ct) {
                const int c = wave * 32 + ct * 16 + bn;
                const long bi = hbase + (long)c * NN + jj;
                short8x Bh = *(const short8x*)(HbfT + bi);
                short8x Bg = *(const short8x*)(GbfT + bi);
                accH[0][ct] = __builtin_amdgcn_mfma_f32_16x16x32_bf16(A0, Bh, accH[0][ct], 0, 0, 0);
                accH[1][ct] = __builtin_amdgcn_mfma_f32_16x16x32_bf16(A1, Bh, accH[1][ct], 0, 0, 0);
                accG[0][ct] = __builtin_amdgcn_mfma_f32_16x16x32_bf16(A0, Bg, accG[0][ct], 0, 0, 0);
                accG[1][ct] = __builtin_amdgcn_mfma_f32_16x16x32_bf16(A1, Bg, accG[1][ct], 0, 0, 0);
            }
        }
    }

    // ---- reduce l per row, invert ----
    __syncthreads();             // sred free (wh2max phase long done); Afrag idle
    sred[rr * 16 + sg] = lloc;
    __syncthreads();
    if (t < 32) {
        float v = sred[t * 16];
#pragma unroll
        for (int k = 1; k < 16; ++k) v += sred[t * 16 + k];
        ssc[t] = 1.0f / v;       // v > 0 always (~half the j's unmasked)
    }
    __syncthreads();

    // ---- scale by 1/l and store (C-layout: col=lane&15, row=(lane>>4)*4+reg)
#pragma unroll
    for (int rt = 0; rt < 2; ++rt)
#pragma unroll
        for (int ct = 0; ct < 2; ++ct) {
            const int c = wave * 32 + ct * 16 + bn;
#pragma unroll
            for (int reg = 0; reg < 4; ++reg) {
                const int rl = rt * 16 + bq * 4 + reg;
                const float il = ssc[rl];
                const long row = gi0 + rl;
                PH[row * IN_F + c] = f2b(accH[rt][ct][reg] * il);
                PG[row * IN_F + c] = f2b(accG[rt][ct][reg] * il);
            }
        }
}

// ---------------------------------------------------------------------------
// epi2: both epilogue GEMMs in one launch.
// blocks [0,512): out0 = ELU(PH @ W1); blocks [512,1024): out1 = ELU(PG @ W2)
// ---------------------------------------------------------------------------
__global__ __launch_bounds__(256) void epi2(const u16* __restrict__ PH,
                                            const u16* __restrict__ PG,
                                            const u16* __restrict__ W1T,
                                            const u16* __restrict__ W2T,
                                            float* __restrict__ out)
{
    int bid = blockIdx.x;
    const u16* X;
    const u16* WT;
    float* o;
    if (bid < 512) { X = PH; WT = W1T; o = out; }
    else           { X = PG; WT = W2T; o = out + (long)BB * NN * IN_F; bid -= 512; }

    const int t = threadIdx.x;
    const int wave = t >> 6, lane = t & 63;
    const long i0 = (long)bid * 32;

    __shared__ __align__(16) u16 Afrag[8 * 2 * 64 * 8];   // 16 KB

    const int m = t >> 3, ks0 = t & 7, rt0 = m >> 4, lm = m & 15;
    const u16* xp = X + (i0 + m) * IN_F + ks0 * 32;
#pragma unroll
    for (int q = 0; q < 4; ++q) {
        short8x v = *(const short8x*)(xp + q * 8);
        *(short8x*)&Afrag[((ks0 * 2 + rt0) * 64 + lm + q * 16) * 8] = v;
    }
    __syncthreads();

    float4x acc[2][4];
#pragma unroll
    for (int rt = 0; rt < 2; ++rt)
#pragma unroll
        for (int ct = 0; ct < 4; ++ct) acc[rt][ct] = (float4x)0.0f;

    const int bn = lane & 15, bq = lane >> 4;
#pragma unroll
    for (int ks = 0; ks < 8; ++ks) {
        short8x A0 = *(const short8x*)&Afrag[((ks * 2 + 0) * 64 + lane) * 8];
        short8x A1 = *(const short8x*)&Afrag[((ks * 2 + 1) * 64 + lane) * 8];
#pragma unroll
        for (int ct = 0; ct < 4; ++ct) {
            const int n = wave * 64 + ct * 16 + bn;
            short8x Bw = *(const short8x*)(WT + n * IN_F + ks * 32 + bq * 8);
            acc[0][ct] = __builtin_amdgcn_mfma_f32_16x16x32_bf16(A0, Bw, acc[0][ct], 0, 0, 0);
            acc[1][ct] = __builtin_amdgcn_mfma_f32_16x16x32_bf16(A1, Bw, acc[1][ct], 0, 0, 0);
        }
    }

#pragma unroll
    for (int rt = 0; rt < 2; ++rt)
#pragma unroll
        for (int ct = 0; ct < 4; ++ct) {
            const int n = wave * 64 + ct * 16 + bn;
#pragma unroll
            for (int reg = 0; reg < 4; ++reg) {
                const long row = i0 + rt * 16 + bq * 4 + reg;
                float v = acc[rt][ct][reg];
                v = (v > 0.f) ? v : (__expf(v) - 1.f);   // ELU
                o[row * IN_F + n] = v;
            }
        }
}

// ---------------------------------------------------------------------------
extern "C" void kernel_launch(void* const* d_in, const int* in_sizes, int n_in,
                              void* d_out, int out_size, void* d_ws, size_t ws_size,
                              hipStream_t stream)
{
    int ih = -1, ig = -1, iadj = -1, iw1 = -1, iw2 = -1, ia = -1;
    for (int i = 0; i < n_in; ++i) {
        int s = in_sizes[i];
        if      (s == BB * NN * NN)   { if (iadj < 0) iadj = i; }
        else if (s == BB * NN * IN_F) { if (ih < 0) ih = i; else if (ig < 0) ig = i; }
        else if (s == IN_F * IN_F)    { if (iw1 < 0) iw1 = i; else if (iw2 < 0) iw2 = i; }
        else if (s == 2 * IN_F)       { if (ia < 0) ia = i; }
    }
    if (ih < 0 || ig < 0 || iadj < 0 || iw1 < 0 || iw2 < 0 || ia < 0) {
        ih = 0; iadj = 1; ig = 2; iw1 = 3; iw2 = 4; ia = 5;
    }
    const float* h     = (const float*)d_in[ih];
    const int*   adj   = (const int*)  d_in[iadj];
    const float* lrgt1 = (const float*)d_in[ig];
    const float* W1    = (const float*)d_in[iw1];
    const float* W2    = (const float*)d_in[iw2];
    const float* a     = (const float*)d_in[ia];
    float* out = (float*)d_out;

    // ws layout — 33,949,696 B total (<= proven-available 34,212,096 B)
    float* ws   = (float*)d_ws;
    float* v1   = ws;                       // 256
    float* v2   = v1 + IN_F;                // 256
    float* Wh1  = v2 + IN_F;                // 16384
    float* Wh2  = Wh1 + BB * NN;            // 16384
    u16* W1T  = (u16*)(Wh2 + BB * NN);      // 65536 bf16
    u16* W2T  = W1T + IN_F * IN_F;          // 65536
    u16* HbfT = W2T + IN_F * IN_F;          // 8*256*2048
    u16* GbfT = HbfT + (long)BB * IN_F * NN;
    u16* PH   = GbfT + (long)BB * IN_F * NN;
    u16* PG   = PH + (long)BB * NN * IN_F;

    const int nrows = BB * NN;

    prep     <<<8321,        256, 0, stream>>>(h, lrgt1, W1, W2, a,
                                               HbfT, GbfT, W1T, W2T, v1, v2);
    rowdots  <<<nrows / 4,   256, 0, stream>>>(h, v1, v2, Wh1, Wh2);
    attn_mfma<<<nrows / 32,  512, 0, stream>>>(adj, HbfT, GbfT, Wh1, Wh2, PH, PG);
    epi2     <<<2 * nrows / 32, 256, 0, stream>>>(PH, PG, W1T, W2T, out);
}